// Round 6
// baseline (1162.460 us; speedup 1.0000x reference)
//
#include <hip/hip_runtime.h>
#include <stdint.h>
#include <string.h>

#define NLEV 16

typedef float  vfloat4 __attribute__((ext_vector_type(4)));   // nontemporal-store-compatible

// ---------------------------------------------------------------------------
// Shared helpers
// ---------------------------------------------------------------------------
__device__ __forceinline__ void norm_coords(const float* __restrict__ xyz, int p,
                                            float& nx, float& ny, float& nz) {
    const float x = __builtin_nontemporal_load(xyz + 3 * p + 0);
    const float y = __builtin_nontemporal_load(xyz + 3 * p + 1);
    const float z = __builtin_nontemporal_load(xyz + 3 * p + 2);
    const float inv = 1.0f / 1.5f;
    nx = (x + 0.75f) * inv;
    ny = (y + 0.75f) * inv;
    nz = (z + 0.75f) * inv;
}

__device__ __forceinline__ float2 trilerp(const float2 v[8],
                                          float fx, float fy, float fz) {
    const float gx = 1.0f - fx, gy = 1.0f - fy, gz = 1.0f - fz;
    const float w00 = gx * gy, w01 = gx * fy, w10 = fx * gy, w11 = fx * fy;
    float w, f0, f1;
    w = w00 * gz; f0 = w * v[0].x;          f1 = w * v[0].y;
    w = w00 * fz; f0 = fmaf(w, v[1].x, f0); f1 = fmaf(w, v[1].y, f1);
    w = w01 * gz; f0 = fmaf(w, v[2].x, f0); f1 = fmaf(w, v[2].y, f1);
    w = w01 * fz; f0 = fmaf(w, v[3].x, f0); f1 = fmaf(w, v[3].y, f1);
    w = w10 * gz; f0 = fmaf(w, v[4].x, f0); f1 = fmaf(w, v[4].y, f1);
    w = w10 * fz; f0 = fmaf(w, v[5].x, f0); f1 = fmaf(w, v[5].y, f1);
    w = w11 * gz; f0 = fmaf(w, v[6].x, f0); f1 = fmaf(w, v[6].y, f1);
    w = w11 * fz; f0 = fmaf(w, v[7].x, f0); f1 = fmaf(w, v[7].y, f1);
    return make_float2(f0, f1);
}

// ---------------------------------------------------------------------------
// Big levels (7..15): ONE point per thread, VGPR target <= 64 so the HW
// occupancy quantum (waves/CU halves at VGPR 64/128/256) gives 32 waves/CU —
// double the 2-pt version's 16. Same total outstanding requests per CU,
// twice the waves to hide issue latency. x-pair trick as before: the
// 16B-aligned float4 chunk at (h0>>1) holds both x-corners when bx is even.
// ---------------------------------------------------------------------------
template<int R, uint32_t OFF>
__global__ __launch_bounds__(256, 8) void big_level1(
    const float* __restrict__ xyz,
    const float2* __restrict__ emb,
    float2* __restrict__ ws,      // level-major slice for this level
    int nb)
{
    const int p = blockIdx.x * 256 + threadIdx.x;
    if (p >= nb) return;

    const float4* __restrict__ emb4 = (const float4*)emb;
    const uint32_t M = 524287u;

    float nx, ny, nz;
    norm_coords(xyz, p, nx, ny, nz);

    const float rf = (float)R;
    const float px = nx * rf, py = ny * rf, pz = nz * rf;
    int bx = (int)floorf(px); bx = bx < 0 ? 0 : (bx > R - 1 ? R - 1 : bx);
    int by = (int)floorf(py); by = by < 0 ? 0 : (by > R - 1 ? R - 1 : by);
    int bz = (int)floorf(pz); bz = bz < 0 ? 0 : (bz > R - 1 ? R - 1 : bz);
    const float fx = px - (float)bx;
    const float fy = py - (float)by;
    const float fz = pz - (float)bz;

    const uint32_t hy0 = (uint32_t)by       * 2654435761u;
    const uint32_t hy1 = (uint32_t)(by + 1) * 2654435761u;
    const uint32_t hz0 = (uint32_t)bz       * 805459861u;
    const uint32_t hz1 = (uint32_t)(bz + 1) * 805459861u;
    uint32_t yzs[4];
    yzs[0] = hy0 ^ hz0; yzs[1] = hy0 ^ hz1;
    yzs[2] = hy1 ^ hz0; yzs[3] = hy1 ^ hz1;

    const uint32_t hx0 = (uint32_t)bx;
    const bool oddbx = (bx & 1) != 0;
    const uint32_t hx1 = hx0 + 1u;

    uint32_t h0[4];
    float4   V[4];
    #pragma unroll
    for (int i = 0; i < 4; ++i) {
        h0[i] = (hx0 ^ yzs[i]) & M;
        V[i]  = emb4[(h0[i] >> 1) + (OFF >> 1)];
    }
    float2 w1[4];
    if (oddbx) {
        #pragma unroll
        for (int i = 0; i < 4; ++i)
            w1[i] = emb[((hx1 ^ yzs[i]) & M) + OFF];
    }

    float2 v[8];
    #pragma unroll
    for (int i = 0; i < 4; ++i) {
        const float2 lo = make_float2(V[i].x, V[i].y);
        const float2 hi = make_float2(V[i].z, V[i].w);
        const bool oh = (h0[i] & 1u) != 0u;
        v[i]     = oh ? hi : lo;
        v[i + 4] = oddbx ? w1[i] : (oh ? lo : hi);
    }
    const float2 r = trilerp(v, fx, fy, fz);

    uint64_t u;
    memcpy(&u, &r, 8);
    __builtin_nontemporal_store(u, (uint64_t*)ws + p);
}

// ---------------------------------------------------------------------------
// Pack kernel: small levels 0..6 inline, merge big-level ws, coalesced out.
// NEW vs round 5:
//  (1) Two-phase 32-record LDS transpose: LDS 35840 -> 17920 B/block, so
//      8 blocks/CU (32 waves, 100% ceiling) instead of 4 (50%).
//  (2) δ-mod trick: a = yz ^ hx differs from yz only in low 7 bits, so
//      a % sz = (yz % sz) + ((w^hx) - w) with one ±sz fixup — ONE 64-bit
//      mod per corner-pair instead of 1.5 avg. Pairing (16B covers both
//      x-corners) detected directly via |h1-h0|==1.
// ---------------------------------------------------------------------------
__global__ __launch_bounds__(256, 8) void pack_small(
    const float* __restrict__ xyz,
    const float2* __restrict__ emb,
    const float2* __restrict__ ws,
    float* __restrict__ out,
    int nb)
{
    constexpr int      kRes[7]  = {16, 20, 25, 32, 40, 50, 64};
    constexpr uint32_t kSize[7] = {4913u, 9261u, 17576u, 35937u, 68921u, 132651u, 274625u};
    constexpr uint32_t kOff[7]  = {0u, 4913u, 14174u, 31750u, 67687u, 136608u, 269259u};

    __shared__ __align__(16) float lds[4][32 * 35];   // 17,920 B

    const int tid  = threadIdx.x;
    const int lane = tid & 63;
    const int wid  = tid >> 6;
    const int p    = blockIdx.x * 256 + tid;
    const int pc   = (p < nb) ? p : (nb - 1);

    // hoist big-level ws loads: 9 HBM reads in flight during all small levels
    uint64_t wsv[9];
    #pragma unroll
    for (int l = 0; l < 9; ++l)
        wsv[l] = __builtin_nontemporal_load(
            (const uint64_t*)ws + (size_t)l * nb + pc);

    const float x = xyz[3 * pc + 0];
    const float y = xyz[3 * pc + 1];
    const float z = xyz[3 * pc + 2];

    float rec[35];
    rec[0] = x; rec[1] = y; rec[2] = z;

    const float inv = 1.0f / 1.5f;
    const float nx = (x + 0.75f) * inv;
    const float ny = (y + 0.75f) * inv;
    const float nz = (z + 0.75f) * inv;

    #pragma unroll
    for (int l = 0; l < 7; ++l) {
        const int      r   = kRes[l];
        const float    rf  = (float)r;
        const uint32_t sz  = kSize[l];
        const uint32_t off = kOff[l];

        const float px = nx * rf, py = ny * rf, pz = nz * rf;
        int bx = (int)floorf(px); bx = bx < 0 ? 0 : (bx > r - 1 ? r - 1 : bx);
        int by = (int)floorf(py); by = by < 0 ? 0 : (by > r - 1 ? r - 1 : by);
        int bz = (int)floorf(pz); bz = bz < 0 ? 0 : (bz > r - 1 ? r - 1 : bz);
        const float fx = px - (float)bx;
        const float fy = py - (float)by;
        const float fz = pz - (float)bz;

        const uint32_t x0 = (uint32_t)bx;
        const uint32_t x1 = x0 + 1u;          // <= 64, fits the 7-bit window
        const uint64_t hy0 = (uint64_t)(uint32_t)by       * 2654435761ull;
        const uint64_t hy1 = (uint64_t)(uint32_t)(by + 1) * 2654435761ull;
        const uint64_t hz0 = (uint64_t)(uint32_t)bz       * 805459861ull;
        const uint64_t hz1 = (uint64_t)(uint32_t)(bz + 1) * 805459861ull;

        const uint64_t yzc[4] = { hy0 ^ hz0, hy0 ^ hz1, hy1 ^ hz0, hy1 ^ hz1 };

        float2 v[8];
        #pragma unroll
        for (int c = 0; c < 4; ++c) {
            const uint64_t yz = yzc[c];
            const uint32_t m  = (uint32_t)(yz % sz);      // one 64-bit mod/pair
            const uint32_t w  = (uint32_t)yz & 127u;      // 7-bit XOR window
            const int d0 = (int)(w ^ x0) - (int)w;
            const int d1 = (int)(w ^ x1) - (int)w;
            int h0 = (int)m + d0;
            h0 += (h0 < 0) ? (int)sz : 0;
            h0 -= (h0 >= (int)sz) ? (int)sz : 0;
            int h1 = (int)m + d1;
            h1 += (h1 < 0) ? (int)sz : 0;
            h1 -= (h1 >= (int)sz) ? (int)sz : 0;

            const int  lo  = h0 < h1 ? h0 : h1;
            const bool ok  = ((h0 > h1 ? h0 : h1) - lo) == 1;  // adjacent slots
            const uint32_t iload = (uint32_t)(ok ? lo : h0) + off;
            // 16B load covers slots iload, iload+1 (8B-aligned dwordx4)
            const float4 V = *(const float4*)(emb + iload);
            float2 w1 = make_float2(0.0f, 0.0f);
            if (!ok) w1 = emb[(uint32_t)h1 + off];
            const float2 loV = make_float2(V.x, V.y);
            const float2 hiV = make_float2(V.z, V.w);
            const bool x0lo = (h0 == lo);
            v[c]     = ok ? (x0lo ? loV : hiV) : loV;   // x0 corner
            v[c + 4] = ok ? (x0lo ? hiV : loV) : w1;    // x1 corner
        }

        const float2 rr = trilerp(v, fx, fy, fz);
        rec[3 + 2 * l] = rr.x;
        rec[4 + 2 * l] = rr.y;
    }

    // big-level results (in flight since kernel start)
    #pragma unroll
    for (int l = 0; l < 9; ++l) {
        float2 bv;
        memcpy(&bv, &wsv[l], 8);
        rec[17 + 2 * l] = bv.x;
        rec[18 + 2 * l] = bv.y;
    }

    const int  wave_gid = blockIdx.x * 4 + wid;
    const bool full     = (wave_gid * 64 < nb);
    float* wbuf = lds[wid];

    // ---- phase A: records 0..31 of this wave ----
    if ((lane >> 5) == 0) {
        float* wl = wbuf + lane * 35;
        #pragma unroll
        for (int c = 0; c < 35; ++c) wl[c] = rec[c];
    }
    __syncthreads();
    if (full) {
        const vfloat4* s4 = (const vfloat4*)wbuf;
        vfloat4* d4 = (vfloat4*)(out + (size_t)wave_gid * (64 * 35));
        #pragma unroll
        for (int c = 0; c < 4; ++c)
            __builtin_nontemporal_store(s4[c * 64 + lane], &d4[c * 64 + lane]);
        if (lane < 24)
            __builtin_nontemporal_store(s4[256 + lane], &d4[256 + lane]);
    }
    __syncthreads();

    // ---- phase B: records 32..63 ----
    if ((lane >> 5) == 1) {
        float* wl = wbuf + (lane - 32) * 35;
        #pragma unroll
        for (int c = 0; c < 35; ++c) wl[c] = rec[c];
    }
    __syncthreads();
    if (full) {
        const vfloat4* s4 = (const vfloat4*)wbuf;
        vfloat4* d4 = (vfloat4*)(out + (size_t)wave_gid * (64 * 35) + 1120);
        #pragma unroll
        for (int c = 0; c < 4; ++c)
            __builtin_nontemporal_store(s4[c * 64 + lane], &d4[c * 64 + lane]);
        if (lane < 24)
            __builtin_nontemporal_store(s4[256 + lane], &d4[256 + lane]);
    }
}

// ---------------------------------------------------------------------------
// Fallback: monolithic kernel (used only if ws_size < 72 MB)
// ---------------------------------------------------------------------------
__global__ __launch_bounds__(256, 4) void hashgrid_mono(
    const float* __restrict__ xyz,
    const float2* __restrict__ emb,
    float* __restrict__ out,
    int nb)
{
    constexpr int      kRes[NLEV]  = {16,20,25,32,40,50,64,80,101,128,161,203,256,322,406,512};
    constexpr uint32_t kSize[NLEV] = {4913u,9261u,17576u,35937u,68921u,132651u,274625u,
                                      524288u,524288u,524288u,524288u,524288u,
                                      524288u,524288u,524288u,524288u};
    constexpr uint32_t kOff[NLEV]  = {0u,4913u,14174u,31750u,67687u,136608u,269259u,543884u,
                                      1068172u,1592460u,2116748u,2641036u,3165324u,
                                      3689612u,4213900u,4738188u};

    __shared__ __align__(16) float lds[4 * 64 * 35];

    const int tid  = threadIdx.x;
    const int lane = tid & 63;
    const int wid  = tid >> 6;
    const int p    = blockIdx.x * 256 + tid;
    const int pc   = (p < nb) ? p : (nb - 1);

    const float x = xyz[3 * pc + 0];
    const float y = xyz[3 * pc + 1];
    const float z = xyz[3 * pc + 2];

    float* wl = &lds[(wid * 64 + lane) * 35];
    wl[0] = x; wl[1] = y; wl[2] = z;

    const float inv = 1.0f / 1.5f;
    const float nx = (x + 0.75f) * inv;
    const float ny = (y + 0.75f) * inv;
    const float nz = (z + 0.75f) * inv;

    #pragma unroll
    for (int l = 0; l < NLEV; ++l) {
        const int      r   = kRes[l];
        const float    rf  = (float)r;
        const uint32_t sz  = kSize[l];
        const uint32_t off = kOff[l];

        const float px = nx * rf, py = ny * rf, pz = nz * rf;
        int bx = (int)floorf(px); bx = bx < 0 ? 0 : (bx > r - 1 ? r - 1 : bx);
        int by = (int)floorf(py); by = by < 0 ? 0 : (by > r - 1 ? r - 1 : by);
        int bz = (int)floorf(pz); bz = bz < 0 ? 0 : (bz > r - 1 ? r - 1 : bz);
        const float fx = px - (float)bx;
        const float fy = py - (float)by;
        const float fz = pz - (float)bz;

        const uint64_t hx0 = (uint64_t)(uint32_t)bx;
        const uint64_t hx1 = hx0 + 1u;
        const uint64_t hy0 = (uint64_t)(uint32_t)by       * 2654435761ull;
        const uint64_t hy1 = (uint64_t)(uint32_t)(by + 1) * 2654435761ull;
        const uint64_t hz0 = (uint64_t)(uint32_t)bz       * 805459861ull;
        const uint64_t hz1 = (uint64_t)(uint32_t)(bz + 1) * 805459861ull;

        const uint64_t yz00 = hy0 ^ hz0, yz01 = hy0 ^ hz1;
        const uint64_t yz10 = hy1 ^ hz0, yz11 = hy1 ^ hz1;

        const uint32_t i000 = (uint32_t)((hx0 ^ yz00) % sz) + off;
        const uint32_t i001 = (uint32_t)((hx0 ^ yz01) % sz) + off;
        const uint32_t i010 = (uint32_t)((hx0 ^ yz10) % sz) + off;
        const uint32_t i011 = (uint32_t)((hx0 ^ yz11) % sz) + off;
        const uint32_t i100 = (uint32_t)((hx1 ^ yz00) % sz) + off;
        const uint32_t i101 = (uint32_t)((hx1 ^ yz01) % sz) + off;
        const uint32_t i110 = (uint32_t)((hx1 ^ yz10) % sz) + off;
        const uint32_t i111 = (uint32_t)((hx1 ^ yz11) % sz) + off;

        const float2 v000 = emb[i000];
        const float2 v001 = emb[i001];
        const float2 v010 = emb[i010];
        const float2 v011 = emb[i011];
        const float2 v100 = emb[i100];
        const float2 v101 = emb[i101];
        const float2 v110 = emb[i110];
        const float2 v111 = emb[i111];

        const float gx = 1.0f - fx, gy = 1.0f - fy, gz = 1.0f - fz;
        const float w00 = gx * gy, w01 = gx * fy, w10 = fx * gy, w11 = fx * fy;

        float w, f0, f1;
        w = w00 * gz; f0 = w * v000.x;          f1 = w * v000.y;
        w = w00 * fz; f0 = fmaf(w, v001.x, f0); f1 = fmaf(w, v001.y, f1);
        w = w01 * gz; f0 = fmaf(w, v010.x, f0); f1 = fmaf(w, v010.y, f1);
        w = w01 * fz; f0 = fmaf(w, v011.x, f0); f1 = fmaf(w, v011.y, f1);
        w = w10 * gz; f0 = fmaf(w, v100.x, f0); f1 = fmaf(w, v100.y, f1);
        w = w10 * fz; f0 = fmaf(w, v101.x, f0); f1 = fmaf(w, v101.y, f1);
        w = w11 * gz; f0 = fmaf(w, v110.x, f0); f1 = fmaf(w, v110.y, f1);
        w = w11 * fz; f0 = fmaf(w, v111.x, f0); f1 = fmaf(w, v111.y, f1);

        wl[3 + 2 * l] = f0;
        wl[4 + 2 * l] = f1;
    }

    __syncthreads();

    const int wave_gid = blockIdx.x * 4 + wid;
    if (wave_gid * 64 < nb) {
        const float* src = &lds[wid * 64 * 35];
        float* dst = out + (size_t)wave_gid * (64 * 35);
        #pragma unroll
        for (int c = 0; c < 35; ++c)
            dst[c * 64 + lane] = src[c * 64 + lane];
    }
}

// ---------------------------------------------------------------------------
extern "C" void kernel_launch(void* const* d_in, const int* in_sizes, int n_in,
                              void* d_out, int out_size, void* d_ws, size_t ws_size,
                              hipStream_t stream) {
    const float*  xyz = (const float*)d_in[0];
    const float2* emb = (const float2*)d_in[1];
    float*        out = (float*)d_out;
    const int nb = in_sizes[0] / 3;             // 1,000,000
    const int blocks = (nb + 255) / 256;        // 3907 (pack AND big levels, 1 pt/thread)

    const size_t ws_need = (size_t)9 * (size_t)nb * sizeof(float2);  // 72 MB
    if (ws_size < ws_need) {
        hashgrid_mono<<<blocks, 256, 0, stream>>>(xyz, emb, out, nb);
        return;
    }

    float2* ws = (float2*)d_ws;
    // levels 7..15: R = {80,101,128,161,203,256,322,406,512}
    big_level1< 80,  543884u><<<blocks, 256, 0, stream>>>(xyz, emb, ws + (size_t)0 * nb, nb);
    big_level1<101, 1068172u><<<blocks, 256, 0, stream>>>(xyz, emb, ws + (size_t)1 * nb, nb);
    big_level1<128, 1592460u><<<blocks, 256, 0, stream>>>(xyz, emb, ws + (size_t)2 * nb, nb);
    big_level1<161, 2116748u><<<blocks, 256, 0, stream>>>(xyz, emb, ws + (size_t)3 * nb, nb);
    big_level1<203, 2641036u><<<blocks, 256, 0, stream>>>(xyz, emb, ws + (size_t)4 * nb, nb);
    big_level1<256, 3165324u><<<blocks, 256, 0, stream>>>(xyz, emb, ws + (size_t)5 * nb, nb);
    big_level1<322, 3689612u><<<blocks, 256, 0, stream>>>(xyz, emb, ws + (size_t)6 * nb, nb);
    big_level1<406, 4213900u><<<blocks, 256, 0, stream>>>(xyz, emb, ws + (size_t)7 * nb, nb);
    big_level1<512, 4738188u><<<blocks, 256, 0, stream>>>(xyz, emb, ws + (size_t)8 * nb, nb);
    pack_small<<<blocks, 256, 0, stream>>>(xyz, emb, ws, out, nb);
}